// Round 3
// baseline (345.622 us; speedup 1.0000x reference)
//
#include <hip/hip_runtime.h>
#include <math.h>

#define Bb 8
#define Vv 3
#define Ss 1200
#define Ff 16
#define Hh 32
#define Kk 10
#define STEPS 12
#define ROWS (Bb*Vv*Ss)          // 28800
#define L (Vv*Ss)                // 3600

// ---------------- Kernel A: Wh = feat @ W_gat  (+ f = Wh.a1, g = Wh.a2) ----------------
__global__ __launch_bounds__(256) void gat_wh_k(const float* __restrict__ feat,
                                                const float* __restrict__ W_gat,
                                                const float* __restrict__ a_gat,
                                                float* __restrict__ Wh,
                                                float* __restrict__ fvec,
                                                float* __restrict__ gvec) {
    int blk = blockIdx.x;                 // b*450 + v*150 + c
    int c = blk % 150;
    int v = (blk / 150) % Vv;
    int b = blk / (150 * Vv);
    int tid = threadIdx.x;
    int r = tid >> 5;                     // 0..7 row-in-block
    int h = tid & 31;
    int s = c * 8 + r;

    __shared__ float Wg[16][32];
    __shared__ float fe[8][16];
    for (int i = tid; i < 512; i += 256) Wg[i >> 5][i & 31] = W_gat[v * 512 + i];
    for (int i = tid; i < 128; i += 256) fe[i >> 4][i & 15] = feat[(b * Ss + c * 8) * Ff + i];
    __syncthreads();

    float acc = 0.f;
#pragma unroll
    for (int k = 0; k < 16; ++k) acc += fe[r][k] * Wg[k][h];

    int row = (b * Vv + v) * Ss + s;
    Wh[(size_t)row * Hh + h] = acc;

    float a1 = a_gat[v * 64 + h];
    float a2 = a_gat[v * 64 + 32 + h];
    float pf = acc * a1, pg = acc * a2;
#pragma unroll
    for (int m = 16; m >= 1; m >>= 1) {
        pf += __shfl_xor(pf, m);
        pg += __shfl_xor(pg, m);
    }
    if (h == 0) { fvec[row] = pf; gvec[row] = pg; }
}

// ---------------- Kernel A2: Gmax[b,v] = max_t g[b,v,t] ----------------
__global__ __launch_bounds__(256) void gmax_k(const float* __restrict__ gvec,
                                              float* __restrict__ Gmax) {
    int bv = blockIdx.x;
    int tid = threadIdx.x;
    float m = -3.0e38f;
    for (int t = tid; t < Ss; t += 256) m = fmaxf(m, gvec[bv * Ss + t]);
#pragma unroll
    for (int mm = 32; mm >= 1; mm >>= 1) m = fmaxf(m, __shfl_xor(m, mm));
    __shared__ float red[4];
    if ((tid & 63) == 0) red[tid >> 6] = m;
    __syncthreads();
    if (tid == 0) Gmax[bv] = fmaxf(fmaxf(red[0], red[1]), fmaxf(red[2], red[3]));
}

// ---------------- Kernel B: wave-per-row sparse GAT attention + fused qkv ----------------
// One 64-lane wave per row; 64-thread block so __syncthreads is barrier-free.
// 5 rounds: float4 scan (prefetched) -> ballot compaction -> 2-group gather.
__global__ __launch_bounds__(64) void gat_row_k(const float* __restrict__ adj,
                                                const float* __restrict__ Wh,
                                                const float* __restrict__ fvec,
                                                const float* __restrict__ gvec,
                                                const float* __restrict__ Gmax,
                                                const float* __restrict__ qkv_W,
                                                const float* __restrict__ qkv_b,
                                                float* __restrict__ hsel,
                                                float* __restrict__ qkv) {
    int row = blockIdx.x;                 // (b*3+v)*1200 + s
    int bv = row / Ss;
    int s = row - bv * Ss;
    int lane = threadIdx.x;
    const float* Whbv = Wh + (size_t)bv * Ss * Hh;

    __shared__ int   ct[256];
    __shared__ float cp[256];
    __shared__ float hfL[32];

    float fr = fvec[row];
    float M = fr + Gmax[bv];
    M = (M > 0.f) ? M : 0.2f * M;         // leaky_relu of bound >= true row max

    int h = lane & 31, grp = lane >> 5;
    float acc = 0.f, psum = 0.f;
    const float4* a4p = (const float4*)(adj + (size_t)row * Ss);
    const float4* g4p = (const float4*)(gvec + (size_t)bv * Ss);
    const float4 z4 = make_float4(0.f, 0.f, 0.f, 0.f);

    bool val0 = lane < 300;
    float4 a4 = val0 ? a4p[lane] : z4;
    float4 g4 = val0 ? g4p[lane] : z4;

    for (int r = 0; r < 5; ++r) {
        int i4n = (r + 1) * 64 + lane;
        bool valn = (r < 4) && (i4n < 300);
        float4 a4n = valn ? a4p[i4n] : z4;
        float4 g4n = valn ? g4p[i4n] : z4;

        float av[4] = {a4.x, a4.y, a4.z, a4.w};
        float gg[4] = {g4.x, g4.y, g4.z, g4.w};
        int i4c = r * 64 + lane;
        int base = 0;
#pragma unroll
        for (int k = 0; k < 4; ++k) {
            bool nz = av[k] > 0.f;
            float e = fr + gg[k];
            e = (e > 0.f) ? e : 0.2f * e;
            float p = __expf(e - M);
            unsigned long long mask = __ballot(nz);
            if (nz) {
                int pos = base + __popcll(mask & ((1ull << lane) - 1ull));
                ct[pos] = i4c * 4 + k;
                cp[pos] = p;
                psum += p;
            }
            base += __popcll(mask);
        }
        __syncthreads();                  // single wave: waitcnt only
        for (int j = grp; j < base; j += 2)
            acc += cp[j] * Whbv[(size_t)ct[j] * Hh + h];
        __syncthreads();
        a4 = a4n; g4 = g4n;
    }

#pragma unroll
    for (int m = 32; m >= 1; m >>= 1) psum += __shfl_xor(psum, m);
    acc += __shfl_xor(acc, 32);
    float hv = 0.f;
    if (lane < 32) {
        float rr = acc / psum;
        hv = (rr > 0.f) ? rr : expm1f(rr);
        hfL[lane] = hv;
    }
    __syncthreads();

    // qkv epilogue: lane computes col=lane; lanes<32 also col=64+lane
    float acc0 = qkv_b[lane];
    float acc1 = (lane < 32) ? qkv_b[64 + lane] : 0.f;
#pragma unroll
    for (int i = 0; i < 32; ++i) {
        float hfv = hfL[i];
        acc0 += hfv * qkv_W[i * 96 + lane];
        if (lane < 32) acc1 += hfv * qkv_W[i * 96 + 64 + lane];
    }
    qkv[(size_t)row * 96 + lane] = acc0;
    if (lane < 32) qkv[(size_t)row * 96 + 64 + lane] = acc1;

    if (lane < 32 && s >= 800 && s < 811) {
        int b = bv / Vv, v = bv - b * Vv, si = s - 800;
        hsel[(((size_t)b * Vv + v) * 11 + si) * Hh + lane] = hv;
    }
}

// ---------------- Kernel D: self-attn, 3 queries (v=0,1,2) per block ----------------
// Block per (b, si): 88 blocks. K staged in LDS coalesced; V read once for 3 queries.
__global__ __launch_bounds__(256) void attn3_k(const float* __restrict__ hsel,
                                               const float* __restrict__ qkv,
                                               const float* __restrict__ o_W,
                                               const float* __restrict__ o_b,
                                               const float* __restrict__ fus_W,
                                               const float* __restrict__ fus_b,
                                               float* __restrict__ hfg) {
    int blk = blockIdx.x;                 // b*11 + si
    int b = blk / 11;
    int si = blk % 11;
    int s = 800 + si;
    int tid = threadIdx.x;
    const float inv = 0.1767766952966369f; // 1/sqrt(32)

    __shared__ float kS[256][33];         // padded
    __shared__ float pl[3][L];
    __shared__ float qv[3][32];
    __shared__ float red[3][4];
    __shared__ float part[3][8][32];
    __shared__ float sa[3][32];
    __shared__ float hfS[3][32];

    if (tid < 96) {
        int q = tid >> 5, i = tid & 31;
        qv[q][i] = qkv[((size_t)b * L + q * Ss + s) * 96 + i];
    }
    __syncthreads();

    // ---- logits into pl, tracking per-thread max ----
    float lmax0 = -3.0e38f, lmax1 = -3.0e38f, lmax2 = -3.0e38f;
    for (int m0 = 0; m0 < L; m0 += 256) {
        int nrows = min(256, L - m0);
        int c = tid & 7, r0 = tid >> 3;
#pragma unroll
        for (int p = 0; p < 8; ++p) {
            int r = r0 + p * 32;
            if (r < nrows) {
                float4 kv4 = ((const float4*)(qkv + ((size_t)b * L + m0 + r) * 96 + 32))[c];
                kS[r][c * 4 + 0] = kv4.x; kS[r][c * 4 + 1] = kv4.y;
                kS[r][c * 4 + 2] = kv4.z; kS[r][c * 4 + 3] = kv4.w;
            }
        }
        __syncthreads();
        if (tid < nrows) {
            float d0 = 0.f, d1 = 0.f, d2 = 0.f;
#pragma unroll
            for (int i = 0; i < 32; ++i) {
                float kv = kS[tid][i];
                d0 += qv[0][i] * kv; d1 += qv[1][i] * kv; d2 += qv[2][i] * kv;
            }
            d0 *= inv; d1 *= inv; d2 *= inv;
            pl[0][m0 + tid] = d0; pl[1][m0 + tid] = d1; pl[2][m0 + tid] = d2;
            lmax0 = fmaxf(lmax0, d0); lmax1 = fmaxf(lmax1, d1); lmax2 = fmaxf(lmax2, d2);
        }
        __syncthreads();
    }

    // ---- block-reduce lmax per q ----
    float lm[3] = {lmax0, lmax1, lmax2};
#pragma unroll
    for (int q = 0; q < 3; ++q) {
        float m = lm[q];
#pragma unroll
        for (int off = 32; off >= 1; off >>= 1) m = fmaxf(m, __shfl_xor(m, off));
        if ((tid & 63) == 0) red[q][tid >> 6] = m;
    }
    __syncthreads();
    float LM0 = fmaxf(fmaxf(red[0][0], red[0][1]), fmaxf(red[0][2], red[0][3]));
    float LM1 = fmaxf(fmaxf(red[1][0], red[1][1]), fmaxf(red[1][2], red[1][3]));
    float LM2 = fmaxf(fmaxf(red[2][0], red[2][1]), fmaxf(red[2][2], red[2][3]));
    __syncthreads();

    // ---- exp + sum ----
    float ls0 = 0.f, ls1 = 0.f, ls2 = 0.f;
    for (int m = tid; m < L; m += 256) {
        float p0 = __expf(pl[0][m] - LM0);
        float p1 = __expf(pl[1][m] - LM1);
        float p2 = __expf(pl[2][m] - LM2);
        pl[0][m] = p0; pl[1][m] = p1; pl[2][m] = p2;
        ls0 += p0; ls1 += p1; ls2 += p2;
    }
    float lsv[3] = {ls0, ls1, ls2};
#pragma unroll
    for (int q = 0; q < 3; ++q) {
        float v = lsv[q];
#pragma unroll
        for (int off = 32; off >= 1; off >>= 1) v += __shfl_xor(v, off);
        if ((tid & 63) == 0) red[q][tid >> 6] = v;
    }
    __syncthreads();
    float LS0 = red[0][0] + red[0][1] + red[0][2] + red[0][3];
    float LS1 = red[1][0] + red[1][1] + red[1][2] + red[1][3];
    float LS2 = red[2][0] + red[2][1] + red[2][2] + red[2][3];

    // ---- PV: V read once for all 3 queries ----
    int h = tid & 31, mg = tid >> 5;
    float a0 = 0.f, a1 = 0.f, a2 = 0.f;
    for (int m = mg; m < L; m += 8) {
        float vv = qkv[((size_t)b * L + m) * 96 + 64 + h];
        a0 += pl[0][m] * vv; a1 += pl[1][m] * vv; a2 += pl[2][m] * vv;
    }
    part[0][mg][h] = a0; part[1][mg][h] = a1; part[2][mg][h] = a2;
    __syncthreads();

    if (tid < 96) {
        int q = tid >> 5, hh = tid & 31;
        float sacc = 0.f;
#pragma unroll
        for (int j = 0; j < 8; ++j) sacc += part[q][j][hh];
        float LS = (q == 0) ? LS0 : (q == 1) ? LS1 : LS2;
        sa[q][hh] = sacc / LS;
    }
    __syncthreads();
    if (tid < 96) {
        int q = tid >> 5, hh = tid & 31;
        float o = o_b[hh];
#pragma unroll
        for (int i = 0; i < 32; ++i) o += sa[q][i] * o_W[i * 32 + hh];
        float x = hsel[(((size_t)b * Vv + q) * 11 + si) * Hh + hh];
        hfS[q][hh] = 0.8f * o + 0.2f * x;
    }
    __syncthreads();
    if (tid < 96) {
        int q = tid >> 5, hh = tid & 31;
        float gacc = fus_b[hh];
#pragma unroll
        for (int i = 0; i < 32; ++i) gacc += hfS[q][i] * fus_W[i * 32 + hh];
        float gate = 1.f / (1.f + __expf(-gacc));
        hfg[(size_t)(b * 33 + si * 3 + q) * 32 + hh] = gate * hfS[q][hh];
    }
}

// ---------------- Kernel E: scores + softmax + ctx + GRU ----------------
__global__ __launch_bounds__(64) void head_k(const float* __restrict__ hfg,
                                             const float* __restrict__ dis_lab,
                                             const float* __restrict__ att1_W,
                                             const float* __restrict__ att1_b,
                                             const float* __restrict__ att2_W,
                                             const float* __restrict__ att2_b,
                                             const float* __restrict__ Wih,
                                             const float* __restrict__ Whh,
                                             const float* __restrict__ bih,
                                             const float* __restrict__ bhh,
                                             const float* __restrict__ out_W,
                                             const float* __restrict__ out_b,
                                             float* __restrict__ out) {
    int b = blockIdx.x;
    int tid = threadIdx.x;
    __shared__ float lab[11][32];         // rows 0..9 label, 10 unlabel
    __shared__ float sc[10];
    __shared__ float hS[32], xS[32], h2S[32];

    for (int i = tid; i < 352; i += 64) {
        int k = i >> 5, hh = i & 31;
        float val = 0.f;
#pragma unroll
        for (int v = 0; v < 3; ++v) val += hfg[(size_t)(b * 33 + k * 3 + v) * 32 + hh];
        lab[k][hh] = val;
    }
    __syncthreads();

    if (tid < 10) {
        float s_acc = att2_b[0];
        for (int j = 0; j < 32; ++j) {
            float t1 = att1_b[j];
#pragma unroll
            for (int i = 0; i < 32; ++i) t1 += lab[tid][i] * att1_W[i * 32 + j];
#pragma unroll
            for (int i = 0; i < 32; ++i) t1 += lab[10][i] * att1_W[(32 + i) * 32 + j];
            t1 = fmaxf(t1, 0.f);
            s_acc += t1 * att2_W[j];
        }
        sc[tid] = s_acc * dis_lab[b * Kk + tid];
    }
    __syncthreads();
    if (tid == 0) {
        float mx = sc[0];
        for (int k = 1; k < 10; ++k) mx = fmaxf(mx, sc[k]);
        float sm = 0.f;
        for (int k = 0; k < 10; ++k) { sc[k] = __expf(sc[k] - mx); sm += sc[k]; }
        for (int k = 0; k < 10; ++k) sc[k] /= sm;
    }
    __syncthreads();
    if (tid < 32) {
        float c = 0.f;
        for (int k = 0; k < 10; ++k) c += sc[k] * lab[k][tid];
        xS[tid] = c;                      // xt = ctx
        hS[tid] = lab[10][tid];           // h = unlabel
    }
    __syncthreads();

    for (int t = 0; t < STEPS; ++t) {
        float outp = 0.f;
        if (tid < 32) {
            int j = tid;
            float gi_r = bih[j], gi_z = bih[32 + j], gi_n = bih[64 + j];
            float gh_r = bhh[j], gh_z = bhh[32 + j], gh_n = bhh[64 + j];
#pragma unroll
            for (int i = 0; i < 32; ++i) {
                float xv = xS[i], hv = hS[i];
                gi_r += xv * Wih[i * 96 + j];
                gi_z += xv * Wih[i * 96 + 32 + j];
                gi_n += xv * Wih[i * 96 + 64 + j];
                gh_r += hv * Whh[i * 96 + j];
                gh_z += hv * Whh[i * 96 + 32 + j];
                gh_n += hv * Whh[i * 96 + 64 + j];
            }
            float r = 1.f / (1.f + __expf(-(gi_r + gh_r)));
            float z = 1.f / (1.f + __expf(-(gi_z + gh_z)));
            float n = tanhf(gi_n + r * gh_n);
            float hnew = (1.f - z) * n + z * hS[j];
            h2S[j] = hnew;
            outp = hnew * out_W[j];
        }
#pragma unroll
        for (int mm = 16; mm >= 1; mm >>= 1) outp += __shfl_xor(outp, mm);
        if (tid == 0) out[b * STEPS + t] = outp + out_b[0];
        __syncthreads();
        if (tid < 32) { hS[tid] = h2S[tid]; xS[tid] = h2S[tid]; }
        __syncthreads();
    }
}

// ---------------- launcher ----------------
extern "C" void kernel_launch(void* const* d_in, const int* in_sizes, int n_in,
                              void* d_out, int out_size, void* d_ws, size_t ws_size,
                              hipStream_t stream) {
    const float* feat    = (const float*)d_in[0];
    const float* adj     = (const float*)d_in[1];
    const float* dis_lab = (const float*)d_in[2];
    const float* W_gat   = (const float*)d_in[3];
    const float* a_gat   = (const float*)d_in[4];
    const float* qkv_W   = (const float*)d_in[5];
    const float* qkv_b   = (const float*)d_in[6];
    const float* o_W     = (const float*)d_in[7];
    const float* o_b     = (const float*)d_in[8];
    const float* fus_W   = (const float*)d_in[9];
    const float* fus_b   = (const float*)d_in[10];
    const float* att1_W  = (const float*)d_in[11];
    const float* att1_b  = (const float*)d_in[12];
    const float* att2_W  = (const float*)d_in[13];
    const float* att2_b  = (const float*)d_in[14];
    const float* Wih     = (const float*)d_in[15];
    const float* Whh     = (const float*)d_in[16];
    const float* bih     = (const float*)d_in[17];
    const float* bhh     = (const float*)d_in[18];
    const float* out_W   = (const float*)d_in[19];
    const float* out_b   = (const float*)d_in[20];
    float* out = (float*)d_out;

    float* ws = (float*)d_ws;
    float* qkv  = ws;                     // 2764800, live B..D
    float* Wh   = ws + 2764800;           // 921600,  live A..B
    float* fvec = ws + 3686400;           // 28800,   live A..B
    float* gvec = ws + 3715200;           // 28800,   live A..B
    float* Gmax = ws + 3744000;           // 32,      live A2..B
    float* hsel = ws + 3744032;           // 8448,    live B..D
    float* hfg  = ws + 3752480;           // 8448,    live D..E

    gat_wh_k<<<dim3(Bb * Vv * 150), dim3(256), 0, stream>>>(feat, W_gat, a_gat, Wh, fvec, gvec);
    gmax_k<<<dim3(Bb * Vv), dim3(256), 0, stream>>>(gvec, Gmax);
    gat_row_k<<<dim3(ROWS), dim3(64), 0, stream>>>(adj, Wh, fvec, gvec, Gmax,
                                                   qkv_W, qkv_b, hsel, qkv);
    attn3_k<<<dim3(Bb * 11), dim3(256), 0, stream>>>(hsel, qkv, o_W, o_b, fus_W, fus_b, hfg);
    head_k<<<dim3(Bb), dim3(64), 0, stream>>>(hfg, dis_lab, att1_W, att1_b, att2_W, att2_b,
                                              Wih, Whh, bih, bhh, out_W, out_b, out);
}

// Round 4
// 315.216 us; speedup vs baseline: 1.0965x; 1.0965x over previous
//
#include <hip/hip_runtime.h>
#include <math.h>

#define Bb 8
#define Vv 3
#define Ss 1200
#define Ff 16
#define Hh 32
#define Kk 10
#define STEPS 12
#define ROWS (Bb*Vv*Ss)          // 28800
#define L (Vv*Ss)                // 3600

// ---------------- Kernel A: Wh = feat @ W_gat  (+ f = Wh.a1, g = Wh.a2) ----------------
__global__ __launch_bounds__(256) void gat_wh_k(const float* __restrict__ feat,
                                                const float* __restrict__ W_gat,
                                                const float* __restrict__ a_gat,
                                                float* __restrict__ Wh,
                                                float* __restrict__ fvec,
                                                float* __restrict__ gvec) {
    int blk = blockIdx.x;                 // b*450 + v*150 + c
    int c = blk % 150;
    int v = (blk / 150) % Vv;
    int b = blk / (150 * Vv);
    int tid = threadIdx.x;
    int r = tid >> 5;                     // 0..7 row-in-block
    int h = tid & 31;
    int s = c * 8 + r;

    __shared__ float Wg[16][32];
    __shared__ float fe[8][16];
    for (int i = tid; i < 512; i += 256) Wg[i >> 5][i & 31] = W_gat[v * 512 + i];
    for (int i = tid; i < 128; i += 256) fe[i >> 4][i & 15] = feat[(b * Ss + c * 8) * Ff + i];
    __syncthreads();

    float acc = 0.f;
#pragma unroll
    for (int k = 0; k < 16; ++k) acc += fe[r][k] * Wg[k][h];

    int row = (b * Vv + v) * Ss + s;
    Wh[(size_t)row * Hh + h] = acc;

    float a1 = a_gat[v * 64 + h];
    float a2 = a_gat[v * 64 + 32 + h];
    float pf = acc * a1, pg = acc * a2;
#pragma unroll
    for (int m = 16; m >= 1; m >>= 1) {
        pf += __shfl_xor(pf, m);
        pg += __shfl_xor(pg, m);
    }
    if (h == 0) { fvec[row] = pf; gvec[row] = pg; }
}

// ---------------- Kernel A2: Gmax[b,v] = max_t g[b,v,t] ----------------
__global__ __launch_bounds__(256) void gmax_k(const float* __restrict__ gvec,
                                              float* __restrict__ Gmax) {
    int bv = blockIdx.x;
    int tid = threadIdx.x;
    float m = -3.0e38f;
    for (int t = tid; t < Ss; t += 256) m = fmaxf(m, gvec[bv * Ss + t]);
#pragma unroll
    for (int mm = 32; mm >= 1; mm >>= 1) m = fmaxf(m, __shfl_xor(m, mm));
    __shared__ float red[4];
    if ((tid & 63) == 0) red[tid >> 6] = m;
    __syncthreads();
    if (tid == 0) Gmax[bv] = fmaxf(fmaxf(red[0], red[1]), fmaxf(red[2], red[3]));
}

// ---------------- Kernel B: DENSE masked-softmax GEMM + fused qkv ----------------
// Block = 64 output rows of one (b,v). Stream over t in chunks of 64:
// compute P tile (masked exp) into LDS, then register-blocked LDS GEMM.
#define RB 64
#define TCH 64
#define NRB 19                           // ceil(1200/64)
__global__ __launch_bounds__(256) void gat_dense_k(const float* __restrict__ adj,
                                                   const float* __restrict__ Wh,
                                                   const float* __restrict__ fvec,
                                                   const float* __restrict__ gvec,
                                                   const float* __restrict__ Gmax,
                                                   const float* __restrict__ qkv_W,
                                                   const float* __restrict__ qkv_b,
                                                   float* __restrict__ hsel,
                                                   float* __restrict__ qkv) {
    int blk = blockIdx.x;                 // bv*NRB + rb
    int bv = blk / NRB, rb = blk % NRB;
    int row0 = rb * RB;
    int tid = threadIdx.x;

    __shared__ float PS[RB][68];          // stride 68: float4-aligned, 2-way max on write
    __shared__ float WhS[TCH][33];
    __shared__ float psumS[RB];
    __shared__ float hidS[RB][33];

    int pr = tid >> 2, pq = tid & 3;      // P phase: 4 threads per row, 16 t each
    int prow = row0 + pr;
    bool row_ok = prow < Ss;
    int prow_c = row_ok ? prow : (Ss - 1);
    float fr = fvec[bv * Ss + prow_c];
    float M = fr + Gmax[bv];
    float Mr = (M > 0.f) ? M : 0.2f * M;  // leaky_relu of bound >= true row max
    float psum = 0.f;

    int h = tid & 31, rg = tid >> 5;      // FMA phase: rows rg*8..rg*8+7, col h
    float acc[8] = {0.f,0.f,0.f,0.f,0.f,0.f,0.f,0.f};

    const float* adj_r = adj + ((size_t)bv * Ss + prow_c) * Ss;
    const float* g_b   = gvec + (size_t)bv * Ss;
    const float* Wh_b  = Wh + (size_t)bv * Ss * Hh;

    for (int ch = 0; ch < 19; ++ch) {
        int t0 = ch * TCH;
        // stage Wh chunk [t][h]
        for (int idx = tid; idx < TCH * 32; idx += 256) {
            int t = idx >> 5, hh = idx & 31;
            WhS[t][hh] = (t0 + t < Ss) ? Wh_b[(size_t)(t0 + t) * Hh + hh] : 0.f;
        }
        // P tile: p = adj>0 ? exp(lrelu(f_r+g_t) - Mr) : 0
#pragma unroll
        for (int k4 = 0; k4 < 4; ++k4) {
            int tt = pq * 16 + k4 * 4;
            int tg = t0 + tt;
            float4 p4 = make_float4(0.f, 0.f, 0.f, 0.f);
            if (row_ok && tg + 3 < Ss) {
                float4 a4 = *(const float4*)(adj_r + tg);
                float4 g4 = *(const float4*)(g_b + tg);
                float e;
                e = fr + g4.x; e = (e > 0.f) ? e : 0.2f * e; if (a4.x > 0.f) { p4.x = __expf(e - Mr); psum += p4.x; }
                e = fr + g4.y; e = (e > 0.f) ? e : 0.2f * e; if (a4.y > 0.f) { p4.y = __expf(e - Mr); psum += p4.y; }
                e = fr + g4.z; e = (e > 0.f) ? e : 0.2f * e; if (a4.z > 0.f) { p4.z = __expf(e - Mr); psum += p4.z; }
                e = fr + g4.w; e = (e > 0.f) ? e : 0.2f * e; if (a4.w > 0.f) { p4.w = __expf(e - Mr); psum += p4.w; }
            }
            *(float4*)&PS[pr][tt] = p4;
        }
        __syncthreads();
        // GEMM: acc[j] += P[rg*8+j][t] * Wh[t][h]
#pragma unroll 4
        for (int t = 0; t < TCH; t += 4) {
            float w0 = WhS[t][h], w1 = WhS[t+1][h], w2 = WhS[t+2][h], w3 = WhS[t+3][h];
#pragma unroll
            for (int j = 0; j < 8; ++j) {
                float4 p4 = *(const float4*)&PS[rg * 8 + j][t];
                acc[j] += p4.x * w0 + p4.y * w1 + p4.z * w2 + p4.w * w3;
            }
        }
        __syncthreads();
    }

    // row-sum reduce over the 4 pq lanes (aligned groups of 4)
    psum += __shfl_xor(psum, 1);
    psum += __shfl_xor(psum, 2);
    if (pq == 0) psumS[pr] = psum;
    __syncthreads();
#pragma unroll
    for (int j = 0; j < 8; ++j) {
        float r = acc[j] / psumS[rg * 8 + j];
        hidS[rg * 8 + j][h] = (r > 0.f) ? r : expm1f(r);
    }
    __syncthreads();

    int nvalid = Ss - row0; if (nvalid > RB) nvalid = RB;
    // fused qkv projection
    for (int idx = tid; idx < RB * 96; idx += 256) {
        int r = idx / 96, c = idx - r * 96;
        if (r < nvalid) {
            float a = qkv_b[c];
#pragma unroll
            for (int i = 0; i < 32; ++i) a += hidS[r][i] * qkv_W[i * 96 + c];
            qkv[((size_t)bv * Ss + row0 + r) * 96 + c] = a;
        }
    }
    // hsel extraction (s in [800, 811))
    int b = bv / Vv, v = bv - b * Vv;
    for (int idx = tid; idx < 11 * 32; idx += 256) {
        int si = idx >> 5, hh = idx & 31;
        int r = 800 + si - row0;
        if (r >= 0 && r < nvalid)
            hsel[(((size_t)b * Vv + v) * 11 + si) * Hh + hh] = hidS[r][hh];
    }
}

// ---------------- Kernel D1: split-K attention partials ----------------
#define CH 120
#define NCH 30
#define PREC 34                           // per-query record: 32 o + m + l
__global__ __launch_bounds__(256) void attn_part_k(const float* __restrict__ qkv,
                                                   float* __restrict__ part) {
    int blk = blockIdx.x;                 // b*NCH + ch
    int b = blk / NCH, ch = blk % NCH;
    int k0 = ch * CH;
    int tid = threadIdx.x;
    const float inv = 0.1767766952966369f; // 1/sqrt(32)

    __shared__ float qS[33][33];
    __shared__ float kS[CH][33];
    __shared__ float lS[33][124];          // stride 124: float4-aligned
    __shared__ float mS[33], lsS[33];

    for (int idx = tid; idx < 33 * 32; idx += 256) {
        int q = idx >> 5, i = idx & 31;
        int si = q / 3, v = q - si * 3;
        int l = v * Ss + 800 + si;
        qS[q][i] = qkv[((size_t)b * L + l) * 96 + i];
    }
    for (int idx = tid; idx < CH * 32; idx += 256) {
        int r = idx >> 5, i = idx & 31;
        kS[r][i] = qkv[((size_t)b * L + k0 + r) * 96 + 32 + i];
    }
    __syncthreads();

    for (int idx = tid; idx < 33 * CH; idx += 256) {
        int q = idx / CH, k = idx - q * CH;
        float d = 0.f;
#pragma unroll
        for (int i = 0; i < 32; ++i) d += qS[q][i] * kS[k][i];
        lS[q][k] = d * inv;
    }
    __syncthreads();

    // per-query max + exp + sum: 4 lanes per query (aligned)
    int q4 = tid >> 2, j4 = tid & 3;
    if (q4 < 33) {
        float m = -3.0e38f;
        for (int k = j4; k < CH; k += 4) m = fmaxf(m, lS[q4][k]);
        m = fmaxf(m, __shfl_xor(m, 1));
        m = fmaxf(m, __shfl_xor(m, 2));
        float ssum = 0.f;
        for (int k = j4; k < CH; k += 4) {
            float p = __expf(lS[q4][k] - m);
            lS[q4][k] = p;
            ssum += p;
        }
        ssum += __shfl_xor(ssum, 1);
        ssum += __shfl_xor(ssum, 2);
        if (j4 == 0) { mS[q4] = m; lsS[q4] = ssum; }
    }
    __syncthreads();

    // reuse kS for V
    for (int idx = tid; idx < CH * 32; idx += 256) {
        int r = idx >> 5, i = idx & 31;
        kS[r][i] = qkv[((size_t)b * L + k0 + r) * 96 + 64 + i];
    }
    __syncthreads();

    float* po = part + ((size_t)b * NCH + ch) * (33 * PREC);
    for (int idx = tid; idx < 33 * 32; idx += 256) {
        int q = idx >> 5, hh = idx & 31;
        float a = 0.f;
        for (int k = 0; k < CH; k += 4) {
            float4 p4 = *(const float4*)&lS[q][k];
            a += p4.x * kS[k][hh] + p4.y * kS[k+1][hh] + p4.z * kS[k+2][hh] + p4.w * kS[k+3][hh];
        }
        po[q * PREC + hh] = a;
    }
    if (tid < 33) { po[tid * PREC + 32] = mS[tid]; po[tid * PREC + 33] = lsS[tid]; }
}

// ---------------- Kernel D2: combine partials + o-proj + fuse + gate ----------------
__global__ __launch_bounds__(256) void attn_comb_k(const float* __restrict__ part,
                                                   const float* __restrict__ hsel,
                                                   const float* __restrict__ o_W,
                                                   const float* __restrict__ o_b,
                                                   const float* __restrict__ fus_W,
                                                   const float* __restrict__ fus_b,
                                                   float* __restrict__ hfg) {
    int b = blockIdx.x;
    int tid = threadIdx.x;
    __shared__ float RS[33][NCH];
    __shared__ float LSs[33];
    __shared__ float oS[33][33];
    __shared__ float hfS[33][33];
    const float* pb = part + (size_t)b * NCH * (33 * PREC);

    if (tid < 33) {
        float M = -3.0e38f;
        for (int c = 0; c < NCH; ++c) M = fmaxf(M, pb[c * 33 * PREC + tid * PREC + 32]);
        float Lt = 0.f;
        for (int c = 0; c < NCH; ++c) {
            float w = __expf(pb[c * 33 * PREC + tid * PREC + 32] - M);
            RS[tid][c] = w;
            Lt += w * pb[c * 33 * PREC + tid * PREC + 33];
        }
        LSs[tid] = Lt;
    }
    __syncthreads();

    for (int idx = tid; idx < 33 * 32; idx += 256) {
        int q = idx >> 5, hh = idx & 31;
        float a = 0.f;
        for (int c = 0; c < NCH; ++c) a += RS[q][c] * pb[c * 33 * PREC + q * PREC + hh];
        oS[q][hh] = a / LSs[q];
    }
    __syncthreads();
    for (int idx = tid; idx < 33 * 32; idx += 256) {
        int q = idx >> 5, hh = idx & 31;
        int si = q / 3, v = q - si * 3;
        float o = o_b[hh];
#pragma unroll
        for (int i = 0; i < 32; ++i) o += oS[q][i] * o_W[i * 32 + hh];
        float x = hsel[(((size_t)b * Vv + v) * 11 + si) * Hh + hh];
        hfS[q][hh] = 0.8f * o + 0.2f * x;
    }
    __syncthreads();
    for (int idx = tid; idx < 33 * 32; idx += 256) {
        int q = idx >> 5, hh = idx & 31;
        float gacc = fus_b[hh];
#pragma unroll
        for (int i = 0; i < 32; ++i) gacc += hfS[q][i] * fus_W[i * 32 + hh];
        float gate = 1.f / (1.f + __expf(-gacc));
        hfg[(size_t)(b * 33 + q) * 32 + hh] = gate * hfS[q][hh];
    }
}

// ---------------- Kernel E: scores + softmax + ctx + GRU ----------------
__global__ __launch_bounds__(64) void head_k(const float* __restrict__ hfg,
                                             const float* __restrict__ dis_lab,
                                             const float* __restrict__ att1_W,
                                             const float* __restrict__ att1_b,
                                             const float* __restrict__ att2_W,
                                             const float* __restrict__ att2_b,
                                             const float* __restrict__ Wih,
                                             const float* __restrict__ Whh,
                                             const float* __restrict__ bih,
                                             const float* __restrict__ bhh,
                                             const float* __restrict__ out_W,
                                             const float* __restrict__ out_b,
                                             float* __restrict__ out) {
    int b = blockIdx.x;
    int tid = threadIdx.x;
    __shared__ float lab[11][32];
    __shared__ float sc[10];
    __shared__ float hS[32], xS[32], h2S[32];

    for (int i = tid; i < 352; i += 64) {
        int k = i >> 5, hh = i & 31;
        float val = 0.f;
#pragma unroll
        for (int v = 0; v < 3; ++v) val += hfg[(size_t)(b * 33 + k * 3 + v) * 32 + hh];
        lab[k][hh] = val;
    }
    __syncthreads();

    if (tid < 10) {
        float s_acc = att2_b[0];
        for (int j = 0; j < 32; ++j) {
            float t1 = att1_b[j];
#pragma unroll
            for (int i = 0; i < 32; ++i) t1 += lab[tid][i] * att1_W[i * 32 + j];
#pragma unroll
            for (int i = 0; i < 32; ++i) t1 += lab[10][i] * att1_W[(32 + i) * 32 + j];
            t1 = fmaxf(t1, 0.f);
            s_acc += t1 * att2_W[j];
        }
        sc[tid] = s_acc * dis_lab[b * Kk + tid];
    }
    __syncthreads();
    if (tid == 0) {
        float mx = sc[0];
        for (int k = 1; k < 10; ++k) mx = fmaxf(mx, sc[k]);
        float sm = 0.f;
        for (int k = 0; k < 10; ++k) { sc[k] = __expf(sc[k] - mx); sm += sc[k]; }
        for (int k = 0; k < 10; ++k) sc[k] /= sm;
    }
    __syncthreads();
    if (tid < 32) {
        float c = 0.f;
        for (int k = 0; k < 10; ++k) c += sc[k] * lab[k][tid];
        xS[tid] = c;
        hS[tid] = lab[10][tid];
    }
    __syncthreads();

    for (int t = 0; t < STEPS; ++t) {
        float outp = 0.f;
        if (tid < 32) {
            int j = tid;
            float gi_r = bih[j], gi_z = bih[32 + j], gi_n = bih[64 + j];
            float gh_r = bhh[j], gh_z = bhh[32 + j], gh_n = bhh[64 + j];
#pragma unroll
            for (int i = 0; i < 32; ++i) {
                float xv = xS[i], hv = hS[i];
                gi_r += xv * Wih[i * 96 + j];
                gi_z += xv * Wih[i * 96 + 32 + j];
                gi_n += xv * Wih[i * 96 + 64 + j];
                gh_r += hv * Whh[i * 96 + j];
                gh_z += hv * Whh[i * 96 + 32 + j];
                gh_n += hv * Whh[i * 96 + 64 + j];
            }
            float r = 1.f / (1.f + __expf(-(gi_r + gh_r)));
            float z = 1.f / (1.f + __expf(-(gi_z + gh_z)));
            float n = tanhf(gi_n + r * gh_n);
            float hnew = (1.f - z) * n + z * hS[j];
            h2S[j] = hnew;
            outp = hnew * out_W[j];
        }
#pragma unroll
        for (int mm = 16; mm >= 1; mm >>= 1) outp += __shfl_xor(outp, mm);
        if (tid == 0) out[b * STEPS + t] = outp + out_b[0];
        __syncthreads();
        if (tid < 32) { hS[tid] = h2S[tid]; xS[tid] = h2S[tid]; }
        __syncthreads();
    }
}

// ---------------- launcher ----------------
extern "C" void kernel_launch(void* const* d_in, const int* in_sizes, int n_in,
                              void* d_out, int out_size, void* d_ws, size_t ws_size,
                              hipStream_t stream) {
    const float* feat    = (const float*)d_in[0];
    const float* adj     = (const float*)d_in[1];
    const float* dis_lab = (const float*)d_in[2];
    const float* W_gat   = (const float*)d_in[3];
    const float* a_gat   = (const float*)d_in[4];
    const float* qkv_W   = (const float*)d_in[5];
    const float* qkv_b   = (const float*)d_in[6];
    const float* o_W     = (const float*)d_in[7];
    const float* o_b     = (const float*)d_in[8];
    const float* fus_W   = (const float*)d_in[9];
    const float* fus_b   = (const float*)d_in[10];
    const float* att1_W  = (const float*)d_in[11];
    const float* att1_b  = (const float*)d_in[12];
    const float* att2_W  = (const float*)d_in[13];
    const float* att2_b  = (const float*)d_in[14];
    const float* Wih     = (const float*)d_in[15];
    const float* Whh     = (const float*)d_in[16];
    const float* bih     = (const float*)d_in[17];
    const float* bhh     = (const float*)d_in[18];
    const float* out_W   = (const float*)d_in[19];
    const float* out_b   = (const float*)d_in[20];
    float* out = (float*)d_out;

    float* ws = (float*)d_ws;
    // layout (floats):
    //   qkv  @ 0        (2764800)  live: B..D
    //   Wh   @ 2764800  (921600)   live: A..B     (region reused by part)
    //   part @ 2764800  (269280)   live: D1..D2   (Wh dead by then)
    //   fvec @ 3686400  (28800)    live: A..B
    //   gvec @ 3715200  (28800)    live: A..B
    //   Gmax @ 3744000  (32)       live: A2..B
    //   hsel @ 3744032  (8448)     live: B..D2
    //   hfg  @ 3752480  (8448)     live: D2..E
    float* qkv  = ws;
    float* Wh   = ws + 2764800;
    float* part = ws + 2764800;
    float* fvec = ws + 3686400;
    float* gvec = ws + 3715200;
    float* Gmax = ws + 3744000;
    float* hsel = ws + 3744032;
    float* hfg  = ws + 3752480;

    gat_wh_k<<<dim3(Bb * Vv * 150), dim3(256), 0, stream>>>(feat, W_gat, a_gat, Wh, fvec, gvec);
    gmax_k<<<dim3(Bb * Vv), dim3(256), 0, stream>>>(gvec, Gmax);
    gat_dense_k<<<dim3(Bb * Vv * NRB), dim3(256), 0, stream>>>(adj, Wh, fvec, gvec, Gmax,
                                                               qkv_W, qkv_b, hsel, qkv);
    attn_part_k<<<dim3(Bb * NCH), dim3(256), 0, stream>>>(qkv, part);
    attn_comb_k<<<dim3(Bb), dim3(256), 0, stream>>>(part, hsel, o_W, o_b, fus_W, fus_b, hfg);
    head_k<<<dim3(Bb), dim3(64), 0, stream>>>(hfg, dis_lab, att1_W, att1_b, att2_W, att2_b,
                                              Wih, Whh, bih, bhh, out_W, out_b, out);
}

// Round 5
// 198.364 us; speedup vs baseline: 1.7424x; 1.5891x over previous
//
#include <hip/hip_runtime.h>
#include <math.h>

#define Bb 8
#define Vv 3
#define Ss 1200
#define Ff 16
#define Hh 32
#define Kk 10
#define STEPS 12
#define ROWS (Bb*Vv*Ss)          // 28800
#define L (Vv*Ss)                // 3600
#define KPAD 1216                // 38*32

typedef __attribute__((ext_vector_type(8))) short bf16x8;
typedef __attribute__((ext_vector_type(4))) float f32x4;
typedef __attribute__((ext_vector_type(4))) unsigned int u32x4;

__device__ __forceinline__ unsigned int pack_hi2(float x0, float x1) {
    return (__float_as_uint(x1) & 0xFFFF0000u) | (__float_as_uint(x0) >> 16);
}
__device__ __forceinline__ unsigned int pack_lo2(float x0, float x1) {
    float h0 = __uint_as_float(__float_as_uint(x0) & 0xFFFF0000u);
    float h1 = __uint_as_float(__float_as_uint(x1) & 0xFFFF0000u);
    return (__float_as_uint(x1 - h1) & 0xFFFF0000u) | (__float_as_uint(x0 - h0) >> 16);
}

// ---------------- Kernel A: Wh = feat @ W_gat  (+ f = Wh.a1, g = Wh.a2) ----------------
__global__ __launch_bounds__(256) void gat_wh_k(const float* __restrict__ feat,
                                                const float* __restrict__ W_gat,
                                                const float* __restrict__ a_gat,
                                                float* __restrict__ Wh,
                                                float* __restrict__ fvec,
                                                float* __restrict__ gvec) {
    int blk = blockIdx.x;                 // b*450 + v*150 + c
    int c = blk % 150;
    int v = (blk / 150) % Vv;
    int b = blk / (150 * Vv);
    int tid = threadIdx.x;
    int r = tid >> 5;                     // 0..7 row-in-block
    int h = tid & 31;
    int s = c * 8 + r;

    __shared__ float Wg[16][32];
    __shared__ float fe[8][16];
    for (int i = tid; i < 512; i += 256) Wg[i >> 5][i & 31] = W_gat[v * 512 + i];
    for (int i = tid; i < 128; i += 256) fe[i >> 4][i & 15] = feat[(b * Ss + c * 8) * Ff + i];
    __syncthreads();

    float acc = 0.f;
#pragma unroll
    for (int k = 0; k < 16; ++k) acc += fe[r][k] * Wg[k][h];

    int row = (b * Vv + v) * Ss + s;
    Wh[(size_t)row * Hh + h] = acc;

    float a1 = a_gat[v * 64 + h];
    float a2 = a_gat[v * 64 + 32 + h];
    float pf = acc * a1, pg = acc * a2;
#pragma unroll
    for (int m = 16; m >= 1; m >>= 1) {
        pf += __shfl_xor(pf, m);
        pg += __shfl_xor(pg, m);
    }
    if (h == 0) { fvec[row] = pf; gvec[row] = pg; }
}

// ---------------- Kernel A2: Gmax[b,v] = max_t g[b,v,t] ----------------
__global__ __launch_bounds__(256) void gmax_k(const float* __restrict__ gvec,
                                              float* __restrict__ Gmax) {
    int bv = blockIdx.x;
    int tid = threadIdx.x;
    float m = -3.0e38f;
    for (int t = tid; t < Ss; t += 256) m = fmaxf(m, gvec[bv * Ss + t]);
#pragma unroll
    for (int mm = 32; mm >= 1; mm >>= 1) m = fmaxf(m, __shfl_xor(m, mm));
    __shared__ float red[4];
    if ((tid & 63) == 0) red[tid >> 6] = m;
    __syncthreads();
    if (tid == 0) Gmax[bv] = fmaxf(fmaxf(red[0], red[1]), fmaxf(red[2], red[3]));
}

// ---------------- Kernel A3: transpose+split Wh -> WhT_hi/WhT_lo bf16 planes ----------------
// [bv][32 h][KPAD k] bf16, zero-padded k>=1200.
__global__ __launch_bounds__(256) void wht_k(const float* __restrict__ Wh,
                                             ushort* __restrict__ WhT_hi,
                                             ushort* __restrict__ WhT_lo) {
    int bv = blockIdx.x / 19, t = blockIdx.x % 19;
    int s0 = t * 64;
    int tid = threadIdx.x;
    __shared__ float T[64][33];
    for (int idx = tid; idx < 2048; idx += 256) {
        int r = idx >> 5, h = idx & 31;
        T[r][h] = (s0 + r < Ss) ? Wh[((size_t)bv * Ss + s0 + r) * Hh + h] : 0.f;
    }
    __syncthreads();
    int h = tid >> 3, c = tid & 7;        // 32 h x 8 chunks
    unsigned int hb[4], lb[4];
#pragma unroll
    for (int j = 0; j < 4; ++j) {
        float e0 = T[c * 8 + 2 * j][h], e1 = T[c * 8 + 2 * j + 1][h];
        hb[j] = pack_hi2(e0, e1);
        lb[j] = pack_lo2(e0, e1);
    }
    size_t off = ((size_t)bv * 32 + h) * KPAD + s0 + c * 8;
    *(uint4*)(WhT_hi + off) = make_uint4(hb[0], hb[1], hb[2], hb[3]);
    *(uint4*)(WhT_lo + off) = make_uint4(lb[0], lb[1], lb[2], lb[3]);
}

// ---------------- Kernel A4: split qkv_W -> WqT_hi/WqT_lo [96 n][32 k] ----------------
__global__ __launch_bounds__(128) void wsplit_k(const float* __restrict__ qkv_W,
                                                ushort* __restrict__ WqT_hi,
                                                ushort* __restrict__ WqT_lo) {
    int n = threadIdx.x;
    if (n < 96) {
        for (int k = 0; k < 32; ++k) {
            float w = qkv_W[k * 96 + n];
            unsigned int u = __float_as_uint(w);
            float hf = __uint_as_float(u & 0xFFFF0000u);
            WqT_hi[n * 32 + k] = (ushort)(u >> 16);
            WqT_lo[n * 32 + k] = (ushort)(__float_as_uint(w - hf) >> 16);
        }
    }
}

// ---------------- Kernel B: MFMA GAT attention (dense, bf16 3-split) + fused qkv ----------------
// 128 thr = 2 waves; wave tile = 16 rows x 32 cols; K-loop 38 steps of 32.
// A (P) built in registers from adj/gvec; B (WhT planes) 16-B frags from global.
__global__ __launch_bounds__(128) void gat_mfma_k(const float* __restrict__ adj,
                                                  const ushort* __restrict__ WhT_hi,
                                                  const ushort* __restrict__ WhT_lo,
                                                  const float* __restrict__ fvec,
                                                  const float* __restrict__ gvec,
                                                  const float* __restrict__ Gmax,
                                                  const ushort* __restrict__ WqT_hi,
                                                  const ushort* __restrict__ WqT_lo,
                                                  const float* __restrict__ qkv_b,
                                                  float* __restrict__ KV,
                                                  float* __restrict__ qsel,
                                                  float* __restrict__ hsel) {
    int blk = blockIdx.x;
    int bv = blk / 38, tb = blk % 38;
    int wave = threadIdx.x >> 6, lane = threadIdx.x & 63;
    int rowbase = tb * 32 + wave * 16;
    int lr = lane & 15, kg = lane >> 4;
    int b = bv / Vv, v = bv - b * Vv;

    int ar = rowbase + lr;
    int ar_c = (ar < Ss) ? ar : (Ss - 1);
    const float* adj_r = adj + ((size_t)bv * Ss + ar_c) * Ss;
    const float* g_b = gvec + (size_t)bv * Ss;
    float fr = fvec[bv * Ss + ar_c];
    float M = fr + Gmax[bv];
    float Mr = fmaxf(M, 0.2f * M);        // leaky_relu of bound >= true row max

    f32x4 acc0 = {0.f, 0.f, 0.f, 0.f}, acc1 = {0.f, 0.f, 0.f, 0.f};
    float psum = 0.f;
    const ushort* Bh0 = WhT_hi + ((size_t)bv * 32 + lr) * KPAD;
    const ushort* Bl0 = WhT_lo + ((size_t)bv * 32 + lr) * KPAD;

    for (int k0 = 0; k0 < KPAD; k0 += 32) {
        int t0 = k0 + kg * 8;
        bf16x8 bh0 = *(const bf16x8*)(Bh0 + t0);
        bf16x8 bl0 = *(const bf16x8*)(Bl0 + t0);
        bf16x8 bh1 = *(const bf16x8*)(Bh0 + 16 * KPAD + t0);
        bf16x8 bl1 = *(const bf16x8*)(Bl0 + 16 * KPAD + t0);

        float p[8];
        if (t0 < Ss) {
            float4 aA = *(const float4*)(adj_r + t0);
            float4 aB = *(const float4*)(adj_r + t0 + 4);
            float4 gA = *(const float4*)(g_b + t0);
            float4 gB = *(const float4*)(g_b + t0 + 4);
            float av[8] = {aA.x, aA.y, aA.z, aA.w, aB.x, aB.y, aB.z, aB.w};
            float gv[8] = {gA.x, gA.y, gA.z, gA.w, gB.x, gB.y, gB.z, gB.w};
#pragma unroll
            for (int j = 0; j < 8; ++j) {
                float e = fr + gv[j];
                e = fmaxf(e, 0.2f * e);
                float pe = __expf(e - Mr);
                p[j] = (av[j] > 0.f) ? pe : 0.f;
                psum += p[j];
            }
        } else {
#pragma unroll
            for (int j = 0; j < 8; ++j) p[j] = 0.f;
        }
        unsigned int hb[4], lb[4];
#pragma unroll
        for (int j = 0; j < 4; ++j) {
            hb[j] = pack_hi2(p[2 * j], p[2 * j + 1]);
            lb[j] = pack_lo2(p[2 * j], p[2 * j + 1]);
        }
        bf16x8 ah = __builtin_bit_cast(bf16x8, (u32x4){hb[0], hb[1], hb[2], hb[3]});
        bf16x8 al = __builtin_bit_cast(bf16x8, (u32x4){lb[0], lb[1], lb[2], lb[3]});
        acc0 = __builtin_amdgcn_mfma_f32_16x16x32_bf16(ah, bh0, acc0, 0, 0, 0);
        acc0 = __builtin_amdgcn_mfma_f32_16x16x32_bf16(ah, bl0, acc0, 0, 0, 0);
        acc0 = __builtin_amdgcn_mfma_f32_16x16x32_bf16(al, bh0, acc0, 0, 0, 0);
        acc1 = __builtin_amdgcn_mfma_f32_16x16x32_bf16(ah, bh1, acc1, 0, 0, 0);
        acc1 = __builtin_amdgcn_mfma_f32_16x16x32_bf16(ah, bl1, acc1, 0, 0, 0);
        acc1 = __builtin_amdgcn_mfma_f32_16x16x32_bf16(al, bh1, acc1, 0, 0, 0);
    }

    // row-sums: lanes with same (lane&15) hold partial sums of the same row
    psum += __shfl_xor(psum, 16);
    psum += __shfl_xor(psum, 32);

    // C layout: col = lane&15 (+16 for tile1), row = kg*4 + j
    __shared__ float hidS[2][16][36];
#pragma unroll
    for (int j = 0; j < 4; ++j) {
        float ps = __shfl(psum, kg * 4 + j);
        float r0 = acc0[j] / ps;
        float r1 = acc1[j] / ps;
        hidS[wave][kg * 4 + j][lr]      = (r0 > 0.f) ? r0 : expm1f(r0);
        hidS[wave][kg * 4 + j][16 + lr] = (r1 > 0.f) ? r1 : expm1f(r1);
    }
    __syncthreads();

    // ---- fused qkv projection: hid(16x32) @ qkv_W via MFMA (same 3-split) ----
    float4 h4a = *(const float4*)&hidS[wave][lr][8 * kg];
    float4 h4b = *(const float4*)&hidS[wave][lr][8 * kg + 4];
    float hv[8] = {h4a.x, h4a.y, h4a.z, h4a.w, h4b.x, h4b.y, h4b.z, h4b.w};
    unsigned int hhb[4], hlb[4];
#pragma unroll
    for (int j = 0; j < 4; ++j) {
        hhb[j] = pack_hi2(hv[2 * j], hv[2 * j + 1]);
        hlb[j] = pack_lo2(hv[2 * j], hv[2 * j + 1]);
    }
    bf16x8 ahh = __builtin_bit_cast(bf16x8, (u32x4){hhb[0], hhb[1], hhb[2], hhb[3]});
    bf16x8 ahl = __builtin_bit_cast(bf16x8, (u32x4){hlb[0], hlb[1], hlb[2], hlb[3]});

    // K,V tiles: qkv_W cols 32..95 -> WqT rows 32 + t*16 + lr
#pragma unroll
    for (int t = 0; t < 4; ++t) {
        int n = 32 + t * 16 + lr;
        bf16x8 wh = *(const bf16x8*)(WqT_hi + n * 32 + 8 * kg);
        bf16x8 wl = *(const bf16x8*)(WqT_lo + n * 32 + 8 * kg);
        float bias = qkv_b[n];
        f32x4 qa = {bias, bias, bias, bias};
        qa = __builtin_amdgcn_mfma_f32_16x16x32_bf16(ahh, wh, qa, 0, 0, 0);
        qa = __builtin_amdgcn_mfma_f32_16x16x32_bf16(ahh, wl, qa, 0, 0, 0);
        qa = __builtin_amdgcn_mfma_f32_16x16x32_bf16(ahl, wh, qa, 0, 0, 0);
#pragma unroll
        for (int j = 0; j < 4; ++j) {
            int row = rowbase + kg * 4 + j;
            if (row < Ss)
                KV[((size_t)b * L + v * Ss + row) * 64 + t * 16 + lr] = qa[j];
        }
    }
    // q tiles only for the wave holding rows 800..815 (selected rows 800..810)
    if (rowbase == 800) {
#pragma unroll
        for (int t = 0; t < 2; ++t) {
            int n = t * 16 + lr;
            bf16x8 wh = *(const bf16x8*)(WqT_hi + n * 32 + 8 * kg);
            bf16x8 wl = *(const bf16x8*)(WqT_lo + n * 32 + 8 * kg);
            float bias = qkv_b[n];
            f32x4 qa = {bias, bias, bias, bias};
            qa = __builtin_amdgcn_mfma_f32_16x16x32_bf16(ahh, wh, qa, 0, 0, 0);
            qa = __builtin_amdgcn_mfma_f32_16x16x32_bf16(ahh, wl, qa, 0, 0, 0);
            qa = __builtin_amdgcn_mfma_f32_16x16x32_bf16(ahl, wh, qa, 0, 0, 0);
#pragma unroll
            for (int j = 0; j < 4; ++j) {
                int si = kg * 4 + j;
                if (si < 11)
                    qsel[((size_t)b * 33 + si * 3 + v) * 32 + t * 16 + lr] = qa[j];
            }
        }
#pragma unroll
        for (int j = 0; j < 4; ++j) {
            int si = kg * 4 + j;
            if (si < 11) {
                hsel[(((size_t)b * Vv + v) * 11 + si) * 32 + lr]      = hidS[wave][si][lr];
                hsel[(((size_t)b * Vv + v) * 11 + si) * 32 + 16 + lr] = hidS[wave][si][16 + lr];
            }
        }
    }
}

// ---------------- Kernel D1: split-K attention partials ----------------
#define CH 120
#define NCH 30
#define PREC 34                           // per-query record: 32 o + m + l
__global__ __launch_bounds__(256) void attn_part_k(const float* __restrict__ KV,
                                                   const float* __restrict__ qsel,
                                                   float* __restrict__ part) {
    int blk = blockIdx.x;                 // b*NCH + ch
    int b = blk / NCH, ch = blk % NCH;
    int k0 = ch * CH;
    int tid = threadIdx.x;
    const float inv = 0.1767766952966369f; // 1/sqrt(32)

    __shared__ float qS[33][33];
    __shared__ float kS[CH][33];
    __shared__ float lS[33][124];          // stride 124: float4-aligned
    __shared__ float mS[33], lsS[33];

    for (int idx = tid; idx < 33 * 32; idx += 256) {
        int q = idx >> 5, i = idx & 31;
        qS[q][i] = qsel[((size_t)b * 33 + q) * 32 + i];
    }
    for (int idx = tid; idx < CH * 32; idx += 256) {
        int r = idx >> 5, i = idx & 31;
        kS[r][i] = KV[((size_t)b * L + k0 + r) * 64 + i];
    }
    __syncthreads();

    for (int idx = tid; idx < 33 * CH; idx += 256) {
        int q = idx / CH, k = idx - q * CH;
        float d = 0.f;
#pragma unroll
        for (int i = 0; i < 32; ++i) d += qS[q][i] * kS[k][i];
        lS[q][k] = d * inv;
    }
    __syncthreads();

    int q4 = tid >> 2, j4 = tid & 3;
    if (q4 < 33) {
        float m = -3.0e38f;
        for (int k = j4; k < CH; k += 4) m = fmaxf(m, lS[q4][k]);
        m = fmaxf(m, __shfl_xor(m, 1));
        m = fmaxf(m, __shfl_xor(m, 2));
        float ssum = 0.f;
        for (int k = j4; k < CH; k += 4) {
            float p = __expf(lS[q4][k] - m);
            lS[q4][k] = p;
            ssum += p;
        }
        ssum += __shfl_xor(ssum, 1);
        ssum += __shfl_xor(ssum, 2);
        if (j4 == 0) { mS[q4] = m; lsS[q4] = ssum; }
    }
    __syncthreads();

    for (int idx = tid; idx < CH * 32; idx += 256) {
        int r = idx >> 5, i = idx & 31;
        kS[r][i] = KV[((size_t)b * L + k0 + r) * 64 + 32 + i];
    }
    __syncthreads();

    float* po = part + ((size_t)b * NCH + ch) * (33 * PREC);
    for (int idx = tid; idx < 33 * 32; idx += 256) {
        int q = idx >> 5, hh = idx & 31;
        float a = 0.f;
        for (int k = 0; k < CH; k += 4) {
            float4 p4 = *(const float4*)&lS[q][k];
            a += p4.x * kS[k][hh] + p4.y * kS[k+1][hh] + p4.z * kS[k+2][hh] + p4.w * kS[k+3][hh];
        }
        po[q * PREC + hh] = a;
    }
    if (tid < 33) { po[tid * PREC + 32] = mS[tid]; po[tid * PREC + 33] = lsS[tid]; }
}

// ---------------- Kernel D2: combine partials + o-proj + fuse + gate ----------------
__global__ __launch_bounds__(256) void attn_comb_k(const float* __restrict__ part,
                                                   const float* __restrict__ hsel,
                                                   const float* __restrict__ o_W,
                                                   const float* __restrict__ o_b,
                                                   const float* __restrict__ fus_W,
                                                   const float* __restrict__ fus_b,
                                                   float* __restrict__ hfg) {
    int b = blockIdx.x;
    int tid = threadIdx.x;
    __shared__ float RS[33][NCH];
    __shared__ float LSs[33];
    __shared__ float oS[33][33];
    __shared__ float hfS[33][33];
    const float* pb = part + (size_t)b * NCH * (33 * PREC);

    if (tid < 33) {
        float M = -3.0e38f;
        for (int c = 0; c < NCH; ++c) M = fmaxf(M, pb[c * 33 * PREC + tid * PREC + 32]);
        float Lt = 0.f;
        for (int c = 0; c < NCH; ++c) {
            float w = __expf(pb[c * 33 * PREC + tid * PREC + 32] - M);
            RS[tid][c] = w;
            Lt += w * pb[c * 33 * PREC + tid * PREC + 33];
        }
        LSs[tid] = Lt;
    }
    __syncthreads();

    for (int idx = tid; idx < 33 * 32; idx += 256) {
        int q = idx >> 5, hh = idx & 31;
        float a = 0.f;
        for (int c = 0; c < NCH; ++c) a += RS[q][c] * pb[c * 33 * PREC + q * PREC + hh];
        oS[q][hh] = a / LSs[q];
    }
    __syncthreads();
    for (int idx = tid; idx < 33 * 32; idx += 256) {
        int q = idx >> 5, hh = idx & 31;
        int si = q / 3, v = q - si * 3;
        float o = o_b[hh];
#pragma unroll
        for (int i = 0; i < 32; ++i) o += oS[q][i] * o_W[i * 32 + hh];
        float x = hsel[(((size_t)b * Vv + v) * 11 + si) * Hh + hh];
        hfS[q][hh] = 0.8f * o + 0.2f * x;
    }
    __syncthreads();
    for (int idx = tid; idx < 33 * 32; idx += 256) {
        int q = idx >> 5, hh = idx & 31;
        float gacc = fus_b[hh];
#pragma unroll
        for (int i = 0; i < 32; ++i) gacc += hfS[q][i] * fus_W[i * 32 + hh];
        float gate = 1.f / (1.f + __expf(-gacc));
        hfg[(size_t)(b * 33 + q) * 32 + hh] = gate * hfS[q][hh];
    }
}

// ---------------- Kernel E: scores + softmax + ctx + GRU ----------------
__global__ __launch_bounds__(64) void head_k(const float* __restrict__ hfg,
                                             const float* __restrict__ dis_lab,
                                             const float* __restrict__ att1_W,
                                             const float* __restrict__ att1_b,
                                             const float* __restrict__ att2_W,
                                             const float* __restrict__ att2_b,
                                             const float* __restrict__ Wih,
                                             const float* __restrict__ Whh,
                                             const float* __restrict__ bih,
                                             const float* __restrict__ bhh,
                                             const float* __restrict__ out_W,
                                             const float* __restrict__ out_b,
                                             float* __restrict__ out) {
    int b = blockIdx.x;
    int tid = threadIdx.x;
    __shared__ float lab[11][32];
    __shared__ float sc[10];
    __shared__ float hS[32], xS[32], h2S[32];

    for (int i = tid; i < 352; i += 64) {
        int k = i >> 5, hh = i & 31;
        float val = 0.f;
#pragma unroll
        for (int v = 0; v < 3; ++v) val += hfg[(size_t)(b * 33 + k * 3 + v) * 32 + hh];
        lab[k][hh] = val;
    }
    __syncthreads();

    if (tid < 10) {
        float s_acc = att2_b[0];
        for (int j = 0; j < 32; ++j) {
            float t1 = att1_b[j];
#pragma unroll
            for (int i = 0; i < 32; ++i) t1 += lab[tid][i] * att1_W[i * 32 + j];
#pragma unroll
            for (int i = 0; i < 32; ++i) t1 += lab[10][i] * att1_W[(32 + i) * 32 + j];
            t1 = fmaxf(t1, 0.f);
            s_acc += t1 * att2_W[j];
        }
        sc[tid] = s_acc * dis_lab[b * Kk + tid];
    }
    __syncthreads();
    if (tid == 0) {
        float mx = sc[0];
        for (int k = 1; k < 10; ++k) mx = fmaxf(mx, sc[k]);
        float sm = 0.f;
        for (int k = 0; k < 10; ++k) { sc[k] = __expf(sc[k] - mx); sm += sc[k]; }
        for (int k = 0; k < 10; ++k) sc[k] /= sm;
    }
    __syncthreads();
    if (tid < 32) {
        float c = 0.f;
        for (int k = 0; k < 10; ++k) c += sc[k] * lab[k][tid];
        xS[tid] = c;
        hS[tid] = lab[10][tid];
    }
    __syncthreads();

    for (int t = 0; t < STEPS; ++t) {
        float outp = 0.f;
        if (tid < 32) {
            int j = tid;
            float gi_r = bih[j], gi_z = bih[32 + j], gi_n = bih[64 + j];
            float gh_r = bhh[j], gh_z = bhh[32 + j], gh_n = bhh[64 + j];
#pragma unroll
            for (int i = 0; i < 32; ++i) {
                float xv = xS[i], hv = hS[i];
                gi_r += xv * Wih[i * 96 + j];
                gi_z += xv * Wih[i * 96 + 32 + j];
                gi_n += xv * Wih[i * 96 + 64 + j];
                gh_r += hv * Whh[i * 96 + j];
                gh_z += hv * Whh[i * 96 + 32 + j];
                gh_n += hv * Whh[i * 96 + 64 + j];
            }
            float r = 1.f / (1.f + __expf(-(gi_r + gh_r)));
            float z = 1.f / (1.f + __expf(-(gi_z + gh_z)));
            float n = tanhf(gi_n + r * gh_n);
            float hnew = (1.f - z) * n + z * hS[j];
            h2S[j] = hnew;
            outp = hnew * out_W[j];
        }
#pragma unroll
        for (int mm = 16; mm >= 1; mm >>= 1) outp += __shfl_xor(outp, mm);
        if (tid == 0) out[b * STEPS + t] = outp + out_b[0];
        __syncthreads();
        if (tid < 32) { hS[tid] = h2S[tid]; xS[tid] = h2S[tid]; }
        __syncthreads();
    }
}

// ---------------- launcher ----------------
extern "C" void kernel_launch(void* const* d_in, const int* in_sizes, int n_in,
                              void* d_out, int out_size, void* d_ws, size_t ws_size,
                              hipStream_t stream) {
    const float* feat    = (const float*)d_in[0];
    const float* adj     = (const float*)d_in[1];
    const float* dis_lab = (const float*)d_in[2];
    const float* W_gat   = (const float*)d_in[3];
    const float* a_gat   = (const float*)d_in[4];
    const float* qkv_W   = (const float*)d_in[5];
    const float* qkv_b   = (const float*)d_in[6];
    const float* o_W     = (const float*)d_in[7];
    const float* o_b     = (const float*)d_in[8];
    const float* fus_W   = (const float*)d_in[9];
    const float* fus_b   = (const float*)d_in[10];
    const float* att1_W  = (const float*)d_in[11];
    const float* att1_b  = (const float*)d_in[12];
    const float* att2_W  = (const float*)d_in[13];
    const float* att2_b  = (const float*)d_in[14];
    const float* Wih     = (const float*)d_in[15];
    const float* Whh     = (const float*)d_in[16];
    const float* bih     = (const float*)d_in[17];
    const float* bhh     = (const float*)d_in[18];
    const float* out_W   = (const float*)d_in[19];
    const float* out_b   = (const float*)d_in[20];
    float* out = (float*)d_out;

    float* ws = (float*)d_ws;
    // layout (floats):
    //   region0 @ 0: Wh (A..wht, 921600) then KV (gat..attn, 1843200)
    //   fvec    @ 1843200 (28800)
    //   gvec    @ 1872000 (28800)
    //   Gmax    @ 1900800 (32)
    //   WhT_hi  @ 1900832 (466944 fl = 933888 ush)  -> overlaid by part (269280) after gat
    //   WhT_lo  @ 2367776 (466944 fl)
    //   qsel    @ 2834720 (8448)
    //   hsel    @ 2843168 (8448)
    //   hfg     @ 2851616 (8448)
    //   WqT_hi  @ 2860064 (1536 fl = 3072 ush)
    //   WqT_lo  @ 2861600 (1536 fl)
    //   total 2863136 floats = 11.45 MB
    float*  Wh     = ws;
    float*  KV     = ws;
    float*  fvec   = ws + 1843200;
    float*  gvec   = ws + 1872000;
    float*  Gmax   = ws + 1900800;
    ushort* WhT_hi = (ushort*)(ws + 1900832);
    float*  part   = ws + 1900832;
    ushort* WhT_lo = (ushort*)(ws + 2367776);
    float*  qsel   = ws + 2834720;
    float*  hsel   = ws + 2843168;
    float*  hfg    = ws + 2851616;
    ushort* WqT_hi = (ushort*)(ws + 2860064);
    ushort* WqT_lo = (ushort*)(ws + 2861600);

    gat_wh_k<<<dim3(Bb * Vv * 150), dim3(256), 0, stream>>>(feat, W_gat, a_gat, Wh, fvec, gvec);
    gmax_k<<<dim3(Bb * Vv), dim3(256), 0, stream>>>(gvec, Gmax);
    wht_k<<<dim3(Bb * Vv * 19), dim3(256), 0, stream>>>(Wh, WhT_hi, WhT_lo);
    wsplit_k<<<dim3(1), dim3(128), 0, stream>>>(qkv_W, WqT_hi, WqT_lo);
    gat_mfma_k<<<dim3(Bb * Vv * 38), dim3(128), 0, stream>>>(adj, WhT_hi, WhT_lo,
                                                             fvec, gvec, Gmax,
                                                             WqT_hi, WqT_lo, qkv_b,
                                                             KV, qsel, hsel);
    attn_part_k<<<dim3(Bb * NCH), dim3(256), 0, stream>>>(KV, qsel, part);
    attn_comb_k<<<dim3(Bb), dim3(256), 0, stream>>>(part, hsel, o_W, o_b, fus_W, fus_b, hfg);
    head_k<<<dim3(Bb), dim3(64), 0, stream>>>(hfg, dis_lab, att1_W, att1_b, att2_W, att2_b,
                                              Wih, Whh, bih, bhh, out_W, out_b, out);
}

// Round 6
// 137.477 us; speedup vs baseline: 2.5140x; 1.4429x over previous
//
#include <hip/hip_runtime.h>
#include <math.h>

#define Bb 8
#define Vv 3
#define Ss 1200
#define Ff 16
#define Hh 32
#define Kk 10
#define STEPS 12
#define ROWS (Bb*Vv*Ss)          // 28800
#define L (Vv*Ss)                // 3600
#define KPAD 1216                // 38*32

typedef __attribute__((ext_vector_type(8))) short bf16x8;
typedef __attribute__((ext_vector_type(4))) float f32x4;
typedef __attribute__((ext_vector_type(4))) unsigned int u32x4;

__device__ __forceinline__ unsigned int pack_hi2(float x0, float x1) {
    return (__float_as_uint(x1) & 0xFFFF0000u) | (__float_as_uint(x0) >> 16);
}
__device__ __forceinline__ unsigned int pack_lo2(float x0, float x1) {
    float h0 = __uint_as_float(__float_as_uint(x0) & 0xFFFF0000u);
    float h1 = __uint_as_float(__float_as_uint(x1) & 0xFFFF0000u);
    return (__float_as_uint(x1 - h1) & 0xFFFF0000u) | (__float_as_uint(x0 - h0) >> 16);
}

// ---------------- Kernel A: Wh = feat @ W_gat  (+ f = Wh.a1, g = Wh.a2) ----------------
__global__ __launch_bounds__(256) void gat_wh_k(const float* __restrict__ feat,
                                                const float* __restrict__ W_gat,
                                                const float* __restrict__ a_gat,
                                                float* __restrict__ Wh,
                                                float* __restrict__ fvec,
                                                float* __restrict__ gvec) {
    int blk = blockIdx.x;                 // b*450 + v*150 + c
    int c = blk % 150;
    int v = (blk / 150) % Vv;
    int b = blk / (150 * Vv);
    int tid = threadIdx.x;
    int r = tid >> 5;                     // 0..7 row-in-block
    int h = tid & 31;
    int s = c * 8 + r;

    __shared__ float Wg[16][32];
    __shared__ float fe[8][16];
    for (int i = tid; i < 512; i += 256) Wg[i >> 5][i & 31] = W_gat[v * 512 + i];
    for (int i = tid; i < 128; i += 256) fe[i >> 4][i & 15] = feat[(b * Ss + c * 8) * Ff + i];
    __syncthreads();

    float acc = 0.f;
#pragma unroll
    for (int k = 0; k < 16; ++k) acc += fe[r][k] * Wg[k][h];

    int row = (b * Vv + v) * Ss + s;
    Wh[(size_t)row * Hh + h] = acc;

    float a1 = a_gat[v * 64 + h];
    float a2 = a_gat[v * 64 + 32 + h];
    float pf = acc * a1, pg = acc * a2;
#pragma unroll
    for (int m = 16; m >= 1; m >>= 1) {
        pf += __shfl_xor(pf, m);
        pg += __shfl_xor(pg, m);
    }
    if (h == 0) { fvec[row] = pf; gvec[row] = pg; }
}

// ---------------- Kernel A2: Gmax[b,v] = max_t g[b,v,t] ----------------
__global__ __launch_bounds__(256) void gmax_k(const float* __restrict__ gvec,
                                              float* __restrict__ Gmax) {
    int bv = blockIdx.x;
    int tid = threadIdx.x;
    float m = -3.0e38f;
    for (int t = tid; t < Ss; t += 256) m = fmaxf(m, gvec[bv * Ss + t]);
#pragma unroll
    for (int mm = 32; mm >= 1; mm >>= 1) m = fmaxf(m, __shfl_xor(m, mm));
    __shared__ float red[4];
    if ((tid & 63) == 0) red[tid >> 6] = m;
    __syncthreads();
    if (tid == 0) Gmax[bv] = fmaxf(fmaxf(red[0], red[1]), fmaxf(red[2], red[3]));
}

// ---------------- Kernel A3: transpose+split Wh -> WhT_hi/WhT_lo bf16 planes ----------------
__global__ __launch_bounds__(256) void wht_k(const float* __restrict__ Wh,
                                             ushort* __restrict__ WhT_hi,
                                             ushort* __restrict__ WhT_lo) {
    int bv = blockIdx.x / 19, t = blockIdx.x % 19;
    int s0 = t * 64;
    int tid = threadIdx.x;
    __shared__ float T[64][33];
    for (int idx = tid; idx < 2048; idx += 256) {
        int r = idx >> 5, h = idx & 31;
        T[r][h] = (s0 + r < Ss) ? Wh[((size_t)bv * Ss + s0 + r) * Hh + h] : 0.f;
    }
    __syncthreads();
    int h = tid >> 3, c = tid & 7;        // 32 h x 8 chunks
    unsigned int hb[4], lb[4];
#pragma unroll
    for (int j = 0; j < 4; ++j) {
        float e0 = T[c * 8 + 2 * j][h], e1 = T[c * 8 + 2 * j + 1][h];
        hb[j] = pack_hi2(e0, e1);
        lb[j] = pack_lo2(e0, e1);
    }
    size_t off = ((size_t)bv * 32 + h) * KPAD + s0 + c * 8;
    *(uint4*)(WhT_hi + off) = make_uint4(hb[0], hb[1], hb[2], hb[3]);
    *(uint4*)(WhT_lo + off) = make_uint4(lb[0], lb[1], lb[2], lb[3]);
}

// ---------------- Kernel A4: split qkv_W -> WqT_hi/WqT_lo [96 n][32 k] ----------------
__global__ __launch_bounds__(128) void wsplit_k(const float* __restrict__ qkv_W,
                                                ushort* __restrict__ WqT_hi,
                                                ushort* __restrict__ WqT_lo) {
    int n = threadIdx.x;
    if (n < 96) {
        for (int k = 0; k < 32; ++k) {
            float w = qkv_W[k * 96 + n];
            unsigned int u = __float_as_uint(w);
            float hf = __uint_as_float(u & 0xFFFF0000u);
            WqT_hi[n * 32 + k] = (ushort)(u >> 16);
            WqT_lo[n * 32 + k] = (ushort)(__float_as_uint(w - hf) >> 16);
        }
    }
}

// ---------------- Kernel B: MFMA GAT attention (dense, bf16 3-split) + fused qkv ----------------
__global__ __launch_bounds__(128) void gat_mfma_k(const float* __restrict__ adj,
                                                  const ushort* __restrict__ WhT_hi,
                                                  const ushort* __restrict__ WhT_lo,
                                                  const float* __restrict__ fvec,
                                                  const float* __restrict__ gvec,
                                                  const float* __restrict__ Gmax,
                                                  const ushort* __restrict__ WqT_hi,
                                                  const ushort* __restrict__ WqT_lo,
                                                  const float* __restrict__ qkv_b,
                                                  float* __restrict__ KV,
                                                  float* __restrict__ qsel,
                                                  float* __restrict__ hsel) {
    int blk = blockIdx.x;
    int bv = blk / 38, tb = blk % 38;
    int wave = threadIdx.x >> 6, lane = threadIdx.x & 63;
    int rowbase = tb * 32 + wave * 16;
    int lr = lane & 15, kg = lane >> 4;
    int b = bv / Vv, v = bv - b * Vv;

    int ar = rowbase + lr;
    int ar_c = (ar < Ss) ? ar : (Ss - 1);
    const float* adj_r = adj + ((size_t)bv * Ss + ar_c) * Ss;
    const float* g_b = gvec + (size_t)bv * Ss;
    float fr = fvec[bv * Ss + ar_c];
    float M = fr + Gmax[bv];
    float Mr = fmaxf(M, 0.2f * M);        // leaky_relu of bound >= true row max

    f32x4 acc0 = {0.f, 0.f, 0.f, 0.f}, acc1 = {0.f, 0.f, 0.f, 0.f};
    float psum = 0.f;
    const ushort* Bh0 = WhT_hi + ((size_t)bv * 32 + lr) * KPAD;
    const ushort* Bl0 = WhT_lo + ((size_t)bv * 32 + lr) * KPAD;

    for (int k0 = 0; k0 < KPAD; k0 += 32) {
        int t0 = k0 + kg * 8;
        bf16x8 bh0 = *(const bf16x8*)(Bh0 + t0);
        bf16x8 bl0 = *(const bf16x8*)(Bl0 + t0);
        bf16x8 bh1 = *(const bf16x8*)(Bh0 + 16 * KPAD + t0);
        bf16x8 bl1 = *(const bf16x8*)(Bl0 + 16 * KPAD + t0);

        float p[8];
        if (t0 < Ss) {
            float4 aA = *(const float4*)(adj_r + t0);
            float4 aB = *(const float4*)(adj_r + t0 + 4);
            float4 gA = *(const float4*)(g_b + t0);
            float4 gB = *(const float4*)(g_b + t0 + 4);
            float av[8] = {aA.x, aA.y, aA.z, aA.w, aB.x, aB.y, aB.z, aB.w};
            float gv[8] = {gA.x, gA.y, gA.z, gA.w, gB.x, gB.y, gB.z, gB.w};
#pragma unroll
            for (int j = 0; j < 8; ++j) {
                float e = fr + gv[j];
                e = fmaxf(e, 0.2f * e);
                float pe = __expf(e - Mr);
                p[j] = (av[j] > 0.f) ? pe : 0.f;
                psum += p[j];
            }
        } else {
#pragma unroll
            for (int j = 0; j < 8; ++j) p[j] = 0.f;
        }
        unsigned int hb[4], lb[4];
#pragma unroll
        for (int j = 0; j < 4; ++j) {
            hb[j] = pack_hi2(p[2 * j], p[2 * j + 1]);
            lb[j] = pack_lo2(p[2 * j], p[2 * j + 1]);
        }
        bf16x8 ah = __builtin_bit_cast(bf16x8, (u32x4){hb[0], hb[1], hb[2], hb[3]});
        bf16x8 al = __builtin_bit_cast(bf16x8, (u32x4){lb[0], lb[1], lb[2], lb[3]});
        acc0 = __builtin_amdgcn_mfma_f32_16x16x32_bf16(ah, bh0, acc0, 0, 0, 0);
        acc0 = __builtin_amdgcn_mfma_f32_16x16x32_bf16(ah, bl0, acc0, 0, 0, 0);
        acc0 = __builtin_amdgcn_mfma_f32_16x16x32_bf16(al, bh0, acc0, 0, 0, 0);
        acc1 = __builtin_amdgcn_mfma_f32_16x16x32_bf16(ah, bh1, acc1, 0, 0, 0);
        acc1 = __builtin_amdgcn_mfma_f32_16x16x32_bf16(ah, bl1, acc1, 0, 0, 0);
        acc1 = __builtin_amdgcn_mfma_f32_16x16x32_bf16(al, bh1, acc1, 0, 0, 0);
    }

    psum += __shfl_xor(psum, 16);
    psum += __shfl_xor(psum, 32);

    __shared__ float hidS[2][16][36];
#pragma unroll
    for (int j = 0; j < 4; ++j) {
        float ps = __shfl(psum, kg * 4 + j);
        float r0 = acc0[j] / ps;
        float r1 = acc1[j] / ps;
        hidS[wave][kg * 4 + j][lr]      = (r0 > 0.f) ? r0 : expm1f(r0);
        hidS[wave][kg * 4 + j][16 + lr] = (r1 > 0.f) ? r1 : expm1f(r1);
    }
    __syncthreads();

    float4 h4a = *(const float4*)&hidS[wave][lr][8 * kg];
    float4 h4b = *(const float4*)&hidS[wave][lr][8 * kg + 4];
    float hv[8] = {h4a.x, h4a.y, h4a.z, h4a.w, h4b.x, h4b.y, h4b.z, h4b.w};
    unsigned int hhb[4], hlb[4];
#pragma unroll
    for (int j = 0; j < 4; ++j) {
        hhb[j] = pack_hi2(hv[2 * j], hv[2 * j + 1]);
        hlb[j] = pack_lo2(hv[2 * j], hv[2 * j + 1]);
    }
    bf16x8 ahh = __builtin_bit_cast(bf16x8, (u32x4){hhb[0], hhb[1], hhb[2], hhb[3]});
    bf16x8 ahl = __builtin_bit_cast(bf16x8, (u32x4){hlb[0], hlb[1], hlb[2], hlb[3]});

#pragma unroll
    for (int t = 0; t < 4; ++t) {
        int n = 32 + t * 16 + lr;
        bf16x8 wh = *(const bf16x8*)(WqT_hi + n * 32 + 8 * kg);
        bf16x8 wl = *(const bf16x8*)(WqT_lo + n * 32 + 8 * kg);
        float bias = qkv_b[n];
        f32x4 qa = {bias, bias, bias, bias};
        qa = __builtin_amdgcn_mfma_f32_16x16x32_bf16(ahh, wh, qa, 0, 0, 0);
        qa = __builtin_amdgcn_mfma_f32_16x16x32_bf16(ahh, wl, qa, 0, 0, 0);
        qa = __builtin_amdgcn_mfma_f32_16x16x32_bf16(ahl, wh, qa, 0, 0, 0);
#pragma unroll
        for (int j = 0; j < 4; ++j) {
            int row = rowbase + kg * 4 + j;
            if (row < Ss)
                KV[((size_t)b * L + v * Ss + row) * 64 + t * 16 + lr] = qa[j];
        }
    }
    if (rowbase == 800) {
#pragma unroll
        for (int t = 0; t < 2; ++t) {
            int n = t * 16 + lr;
            bf16x8 wh = *(const bf16x8*)(WqT_hi + n * 32 + 8 * kg);
            bf16x8 wl = *(const bf16x8*)(WqT_lo + n * 32 + 8 * kg);
            float bias = qkv_b[n];
            f32x4 qa = {bias, bias, bias, bias};
            qa = __builtin_amdgcn_mfma_f32_16x16x32_bf16(ahh, wh, qa, 0, 0, 0);
            qa = __builtin_amdgcn_mfma_f32_16x16x32_bf16(ahh, wl, qa, 0, 0, 0);
            qa = __builtin_amdgcn_mfma_f32_16x16x32_bf16(ahl, wh, qa, 0, 0, 0);
#pragma unroll
            for (int j = 0; j < 4; ++j) {
                int si = kg * 4 + j;
                if (si < 11)
                    qsel[((size_t)b * 33 + si * 3 + v) * 32 + t * 16 + lr] = qa[j];
            }
        }
#pragma unroll
        for (int j = 0; j < 4; ++j) {
            int si = kg * 4 + j;
            if (si < 11) {
                hsel[(((size_t)b * Vv + v) * 11 + si) * 32 + lr]      = hidS[wave][si][lr];
                hsel[(((size_t)b * Vv + v) * 11 + si) * 32 + 16 + lr] = hidS[wave][si][16 + lr];
            }
        }
    }
}

// ---------------- Kernel D1: split-K attention partials ----------------
#define CH 120
#define NCH 30
#define PREC 34                           // per-query record: 32 o + m + l
__global__ __launch_bounds__(256) void attn_part_k(const float* __restrict__ KV,
                                                   const float* __restrict__ qsel,
                                                   float* __restrict__ part) {
    int blk = blockIdx.x;                 // b*NCH + ch
    int b = blk / NCH, ch = blk % NCH;
    int k0 = ch * CH;
    int tid = threadIdx.x;
    const float inv = 0.1767766952966369f; // 1/sqrt(32)

    __shared__ float qS[33][33];
    __shared__ float kS[CH][33];
    __shared__ float lS[33][124];          // stride 124: float4-aligned
    __shared__ float mS[33], lsS[33];

    for (int idx = tid; idx < 33 * 32; idx += 256) {
        int q = idx >> 5, i = idx & 31;
        qS[q][i] = qsel[((size_t)b * 33 + q) * 32 + i];
    }
    for (int idx = tid; idx < CH * 32; idx += 256) {
        int r = idx >> 5, i = idx & 31;
        kS[r][i] = KV[((size_t)b * L + k0 + r) * 64 + i];
    }
    __syncthreads();

    for (int idx = tid; idx < 33 * CH; idx += 256) {
        int q = idx / CH, k = idx - q * CH;
        float d = 0.f;
#pragma unroll
        for (int i = 0; i < 32; ++i) d += qS[q][i] * kS[k][i];
        lS[q][k] = d * inv;
    }
    __syncthreads();

    int q4 = tid >> 2, j4 = tid & 3;
    if (q4 < 33) {
        float m = -3.0e38f;
        for (int k = j4; k < CH; k += 4) m = fmaxf(m, lS[q4][k]);
        m = fmaxf(m, __shfl_xor(m, 1));
        m = fmaxf(m, __shfl_xor(m, 2));
        float ssum = 0.f;
        for (int k = j4; k < CH; k += 4) {
            float p = __expf(lS[q4][k] - m);
            lS[q4][k] = p;
            ssum += p;
        }
        ssum += __shfl_xor(ssum, 1);
        ssum += __shfl_xor(ssum, 2);
        if (j4 == 0) { mS[q4] = m; lsS[q4] = ssum; }
    }
    __syncthreads();

    for (int idx = tid; idx < CH * 32; idx += 256) {
        int r = idx >> 5, i = idx & 31;
        kS[r][i] = KV[((size_t)b * L + k0 + r) * 64 + 32 + i];
    }
    __syncthreads();

    float* po = part + ((size_t)b * NCH + ch) * (33 * PREC);
    for (int idx = tid; idx < 33 * 32; idx += 256) {
        int q = idx >> 5, hh = idx & 31;
        float a = 0.f;
        for (int k = 0; k < CH; k += 4) {
            float4 p4 = *(const float4*)&lS[q][k];
            a += p4.x * kS[k][hh] + p4.y * kS[k+1][hh] + p4.z * kS[k+2][hh] + p4.w * kS[k+3][hh];
        }
        po[q * PREC + hh] = a;
    }
    if (tid < 33) { po[tid * PREC + 32] = mS[tid]; po[tid * PREC + 33] = lsS[tid]; }
}

// ---------------- Kernel D2: combine partials + o-proj + fuse + gate ----------------
__global__ __launch_bounds__(256) void attn_comb_k(const float* __restrict__ part,
                                                   const float* __restrict__ hsel,
                                                   const float* __restrict__ o_W,
                                                   const float* __restrict__ o_b,
                                                   const float* __restrict__ fus_W,
                                                   const float* __restrict__ fus_b,
                                                   float* __restrict__ hfg) {
    int b = blockIdx.x;
    int tid = threadIdx.x;
    __shared__ float RS[33][NCH];
    __shared__ float LSs[33];
    __shared__ float oS[33][33];
    __shared__ float hfS[33][33];
    const float* pb = part + (size_t)b * NCH * (33 * PREC);

    if (tid < 33) {
        float M = -3.0e38f;
        for (int c = 0; c < NCH; ++c) M = fmaxf(M, pb[c * 33 * PREC + tid * PREC + 32]);
        float Lt = 0.f;
        for (int c = 0; c < NCH; ++c) {
            float w = __expf(pb[c * 33 * PREC + tid * PREC + 32] - M);
            RS[tid][c] = w;
            Lt += w * pb[c * 33 * PREC + tid * PREC + 33];
        }
        LSs[tid] = Lt;
    }
    __syncthreads();

    for (int idx = tid; idx < 33 * 32; idx += 256) {
        int q = idx >> 5, hh = idx & 31;
        float a = 0.f;
        for (int c = 0; c < NCH; ++c) a += RS[q][c] * pb[c * 33 * PREC + q * PREC + hh];
        oS[q][hh] = a / LSs[q];
    }
    __syncthreads();
    for (int idx = tid; idx < 33 * 32; idx += 256) {
        int q = idx >> 5, hh = idx & 31;
        int si = q / 3, v = q - si * 3;
        float o = o_b[hh];
#pragma unroll
        for (int i = 0; i < 32; ++i) o += oS[q][i] * o_W[i * 32 + hh];
        float x = hsel[(((size_t)b * Vv + v) * 11 + si) * Hh + hh];
        hfS[q][hh] = 0.8f * o + 0.2f * x;
    }
    __syncthreads();
    for (int idx = tid; idx < 33 * 32; idx += 256) {
        int q = idx >> 5, hh = idx & 31;
        float gacc = fus_b[hh];
#pragma unroll
        for (int i = 0; i < 32; ++i) gacc += hfS[q][i] * fus_W[i * 32 + hh];
        float gate = 1.f / (1.f + __expf(-gacc));
        hfg[(size_t)(b * 33 + q) * 32 + hh] = gate * hfS[q][hh];
    }
}

// ---------------- Kernel E: one-wave LDS-resident scores + softmax + ctx + GRU ----------------
__global__ __launch_bounds__(64) void head_k(const float* __restrict__ hfg,
                                             const float* __restrict__ dis_lab,
                                             const float* __restrict__ att1_W,
                                             const float* __restrict__ att1_b,
                                             const float* __restrict__ att2_W,
                                             const float* __restrict__ att2_b,
                                             const float* __restrict__ Wih,
                                             const float* __restrict__ Whh,
                                             const float* __restrict__ bih,
                                             const float* __restrict__ bhh,
                                             const float* __restrict__ out_W,
                                             const float* __restrict__ out_b,
                                             float* __restrict__ out) {
    int b = blockIdx.x;
    int tid = threadIdx.x;                // one wave (64)
    int j = tid & 31, half = tid >> 5;

    __shared__ float lab[11][32];
    __shared__ float a1T[32][68];         // a1T[j][i] = att1_W[i*32+j], i in [0,64)
    __shared__ float WihT[3][32][36];     // WihT[g][j][i] = Wih[i*96+g*32+j]
    __shared__ float WhhT[3][32][36];
    __shared__ float sc[12];
    __shared__ float xS[32], hS[32];

    // ---- stage lab (sum over v) ----
    for (int i = tid; i < 352; i += 64) {
        int k = i >> 5, hh = i & 31;
        float val = 0.f;
#pragma unroll
        for (int v = 0; v < 3; ++v) val += hfg[(size_t)(b * 33 + k * 3 + v) * 32 + hh];
        lab[k][hh] = val;
    }
    // ---- stage att1_W transposed ----
    for (int idx = tid; idx < 2048; idx += 64) {
        int i = idx >> 5, jj = idx & 31;
        a1T[jj][i] = att1_W[idx];
    }
    // ---- stage GRU weights transposed ----
    for (int idx = tid; idx < 3072; idx += 64) {
        int i = idx / 96, col = idx - i * 96;
        int g = col >> 5, jj = col & 31;
        WihT[g][jj][i] = Wih[idx];
        WhhT[g][jj][i] = Whh[idx];
    }
    __syncthreads();

    // ---- scores: half h handles k = 2*kk + h ----
    float a2w = att2_W[j];
    float a1b = att1_b[j];
    float a2b = att2_b[0];
#pragma unroll
    for (int kk = 0; kk < 5; ++kk) {
        int k = 2 * kk + half;
        float t1 = a1b;
#pragma unroll
        for (int c = 0; c < 8; ++c) {
            float4 lb4 = *(const float4*)&lab[k][c * 4];
            float4 w4  = *(const float4*)&a1T[j][c * 4];
            t1 += lb4.x * w4.x + lb4.y * w4.y + lb4.z * w4.z + lb4.w * w4.w;
        }
#pragma unroll
        for (int c = 0; c < 8; ++c) {
            float4 lb4 = *(const float4*)&lab[10][c * 4];
            float4 w4  = *(const float4*)&a1T[j][32 + c * 4];
            t1 += lb4.x * w4.x + lb4.y * w4.y + lb4.z * w4.z + lb4.w * w4.w;
        }
        float val = fmaxf(t1, 0.f) * a2w;
#pragma unroll
        for (int mm = 16; mm >= 1; mm >>= 1) val += __shfl_xor(val, mm);
        if (j == 0) sc[k] = (val + a2b) * dis_lab[b * Kk + k];
    }
    __syncthreads();
    if (tid == 0) {
        float mx = sc[0];
        for (int k = 1; k < 10; ++k) mx = fmaxf(mx, sc[k]);
        float sm = 0.f;
        for (int k = 0; k < 10; ++k) { sc[k] = __expf(sc[k] - mx); sm += sc[k]; }
        for (int k = 0; k < 10; ++k) sc[k] /= sm;
    }
    __syncthreads();
    if (tid < 32) {
        float c = 0.f;
        for (int k = 0; k < 10; ++k) c += sc[k] * lab[k][tid];
        xS[tid] = c;
        hS[tid] = lab[10][tid];
    }
    __syncthreads();

    // ---- GRU: lane j computes output j; i-range split across the two halves ----
    float b_ir = bih[j], b_iz = bih[32 + j], b_in = bih[64 + j];
    float b_hr = bhh[j], b_hz = bhh[32 + j], b_hn = bhh[64 + j];
    float ow = out_W[j], ob = out_b[0];
    int i0 = half * 16;

    for (int t = 0; t < STEPS; ++t) {
        float gi_r = 0.f, gi_z = 0.f, gi_n = 0.f;
        float gh_r = 0.f, gh_z = 0.f, gh_n = 0.f;
#pragma unroll
        for (int c = 0; c < 4; ++c) {
            float4 x4 = *(const float4*)&xS[i0 + c * 4];
            float4 h4 = *(const float4*)&hS[i0 + c * 4];
            float4 wr = *(const float4*)&WihT[0][j][i0 + c * 4];
            float4 wz = *(const float4*)&WihT[1][j][i0 + c * 4];
            float4 wn = *(const float4*)&WihT[2][j][i0 + c * 4];
            float4 ur = *(const float4*)&WhhT[0][j][i0 + c * 4];
            float4 uz = *(const float4*)&WhhT[1][j][i0 + c * 4];
            float4 un = *(const float4*)&WhhT[2][j][i0 + c * 4];
            gi_r += x4.x * wr.x + x4.y * wr.y + x4.z * wr.z + x4.w * wr.w;
            gi_z += x4.x * wz.x + x4.y * wz.y + x4.z * wz.z + x4.w * wz.w;
            gi_n += x4.x * wn.x + x4.y * wn.y + x4.z * wn.z + x4.w * wn.w;
            gh_r += h4.x * ur.x + h4.y * ur.y + h4.z * ur.z + h4.w * ur.w;
            gh_z += h4.x * uz.x + h4.y * uz.y + h4.z * uz.z + h4.w * uz.w;
            gh_n += h4.x * un.x + h4.y * un.y + h4.z * un.z + h4.w * un.w;
        }
        gi_r += __shfl_xor(gi_r, 32); gi_z += __shfl_xor(gi_z, 32); gi_n += __shfl_xor(gi_n, 32);
        gh_r += __shfl_xor(gh_r, 32); gh_z += __shfl_xor(gh_z, 32); gh_n += __shfl_xor(gh_n, 32);

        float hprev = hS[j];
        float r = 1.f / (1.f + __expf(-(gi_r + b_ir + gh_r + b_hr)));
        float z = 1.f / (1.f + __expf(-(gi_z + b_iz + gh_z + b_hz)));
        float n = tanhf(gi_n + b_in + r * (gh_n + b_hn));
        float hnew = (1.f - z) * n + z * hprev;

        float outp = hnew * ow;
#pragma unroll
        for (int mm = 16; mm >= 1; mm >>= 1) outp += __shfl_xor(outp, mm);
        if (tid == 0) out[b * STEPS + t] = outp + ob;
        __syncthreads();
        if (tid < 32) { hS[tid] = hnew; xS[tid] = hnew; }
        __syncthreads();
    }
}

// ---------------- launcher ----------------
extern "C" void kernel_launch(void* const* d_in, const int* in_sizes, int n_in,
                              void* d_out, int out_size, void* d_ws, size_t ws_size,
                              hipStream_t stream) {
    const float* feat    = (const float*)d_in[0];
    const float* adj     = (const float*)d_in[1];
    const float* dis_lab = (const float*)d_in[2];
    const float* W_gat   = (const float*)d_in[3];
    const float* a_gat   = (const float*)d_in[4];
    const float* qkv_W   = (const float*)d_in[5];
    const float* qkv_b   = (const float*)d_in[6];
    const float* o_W     = (const float*)d_in[7];
    const float* o_b     = (const float*)d_in[8];
    const float* fus_W   = (const float*)d_in[9];
    const float* fus_b   = (const float*)d_in[10];
    const float* att1_W  = (const float*)d_in[11];
    const float* att1_b  = (const float*)d_in[12];
    const float* att2_W  = (const float*)d_in[13];
    const float* att2_b  = (const float*)d_in[14];
    const float* Wih     = (const float*)d_in[15];
    const float* Whh     = (const float*)d_in[16];
    const float* bih     = (const float*)d_in[17];
    const float* bhh     = (const float*)d_in[18];
    const float* out_W   = (const float*)d_in[19];
    const float* out_b   = (const float*)d_in[20];
    float* out = (float*)d_out;

    float* ws = (float*)d_ws;
    float*  Wh     = ws;
    float*  KV     = ws;
    float*  fvec   = ws + 1843200;
    float*  gvec   = ws + 1872000;
    float*  Gmax   = ws + 1900800;
    ushort* WhT_hi = (ushort*)(ws + 1900832);
    float*  part   = ws + 1900832;
    ushort* WhT_lo = (ushort*)(ws + 2367776);
    float*  qsel   = ws + 2834720;
    float*  hsel   = ws + 2843168;
    float*  hfg    = ws + 2851616;
    ushort* WqT_hi = (ushort*)(ws + 2860064);
    ushort* WqT_lo = (ushort*)(ws + 2861600);

    gat_wh_k<<<dim3(Bb * Vv * 150), dim3(256), 0, stream>>>(feat, W_gat, a_gat, Wh, fvec, gvec);
    gmax_k<<<dim3(Bb * Vv), dim3(256), 0, stream>>>(gvec, Gmax);
    wht_k<<<dim3(Bb * Vv * 19), dim3(256), 0, stream>>>(Wh, WhT_hi, WhT_lo);
    wsplit_k<<<dim3(1), dim3(128), 0, stream>>>(qkv_W, WqT_hi, WqT_lo);
    gat_mfma_k<<<dim3(Bb * Vv * 38), dim3(128), 0, stream>>>(adj, WhT_hi, WhT_lo,
                                                             fvec, gvec, Gmax,
                                                             WqT_hi, WqT_lo, qkv_b,
                                                             KV, qsel, hsel);
    attn_part_k<<<dim3(Bb * NCH), dim3(256), 0, stream>>>(KV, qsel, part);
    attn_comb_k<<<dim3(Bb), dim3(256), 0, stream>>>(part, hsel, o_W, o_b, fus_W, fus_b, hfg);
    head_k<<<dim3(Bb), dim3(64), 0, stream>>>(hfg, dis_lab, att1_W, att1_b, att2_W, att2_b,
                                              Wih, Whh, bih, bhh, out_W, out_b, out);
}